// Round 7
// baseline (31.016 us; speedup 1.0000x reference)
//
#include <hip/hip_runtime.h>

#define NB 64
#define NC 206
#define N (NB * NC)        // 13184
#define IPT 4              // positives per thread (256 thr -> 1024 i-window)
#define GX 13              // ceil(N / 1024) worst-case positive coverage
#define GY 64              // group-chunk splits
#define NBLK (GX * GY)     // 832
#define MAXGPB 52          // max groups per chunk = ceil(64*ceil(206/4)/GY)
#define LN2F 0.69314718056f

// Workspace: per-block partials only. Poisoned once to 0xAA by the harness;
// every slot is rewritten by fused_kernel on every call.
struct Ws {
    double partials[NBLK];
    unsigned int npos, nneg;   // written by block (0,0) for the reduce's denom
};

// ---- fused: per-block inline compaction (LDS) + pair loop, no atomics ----
__global__ __launch_bounds__(256) void fused_kernel(
    const float* __restrict__ preds,
    const float* __restrict__ sw,
    const int* __restrict__ labels,
    Ws* __restrict__ ws)
{
    const int bx   = blockIdx.x, by = blockIdx.y;
    const int bid  = by * GX + bx;
    const int wave = threadIdx.x >> 6;   // 0..3
    const int lane = threadIdx.x & 63;

    __shared__ int rowPos[NB], rowNeg[NB];
    __shared__ int posBase[NB], grpBase[NB];
    __shared__ unsigned int totals[2];      // npos, ngroups
    __shared__ float2 sPos[1024];           // this block's positive window
    __shared__ float4 sEG[MAXGPB];          // grouped exp(p_neg), 0-padded
    __shared__ float  sWG[MAXGPB];          // per-group w*ln2
    __shared__ float  wsum[4];

    // pass 1: per-row label counts (wave w owns rows w, w+4, ...)
    for (int r = wave; r < NB; r += 4) {
        int pc = 0, nc = 0;
        for (int c0 = 0; c0 < NC; c0 += 64) {
            int c = c0 + lane;
            int l = (c < NC) ? labels[r * NC + c] : -1;
            pc += __popcll(__ballot(l == 1));
            nc += __popcll(__ballot(l == 0));
        }
        if (lane == 0) { rowPos[r] = pc; rowNeg[r] = nc; }
    }
    __syncthreads();

    // scan: wave 0 exclusive-scans the 64 rows
    if (wave == 0) {
        int pc = rowPos[lane];
        int nc = rowNeg[lane];
        int gc = (nc + 3) >> 2;
        int ip = pc, ig = gc;
        #pragma unroll
        for (int off = 1; off < 64; off <<= 1) {
            int tp = __shfl_up(ip, off, 64);
            int tg = __shfl_up(ig, off, 64);
            if (lane >= off) { ip += tp; ig += tg; }
        }
        posBase[lane] = ip - pc;
        grpBase[lane] = ig - gc;
        if (lane == 63) { totals[0] = (unsigned int)ip; totals[1] = (unsigned int)ig; }
    }
    // zero the group stage while wave 0 scans (no overlap: sEG disjoint from scan data)
    if (threadIdx.x >= 64 && threadIdx.x < 64 + MAXGPB * 4)
        ((float*)sEG)[threadIdx.x - 64] = 0.0f;
    __syncthreads();

    const int npos    = (int)totals[0];
    const int ngroups = (int)totals[1];
    const int i0      = bx * 1024;

    if (i0 >= npos) {                        // block-uniform early-out
        if (threadIdx.x == 0) ws->partials[bid] = 0.0;
        return;
    }
    if (bid == 0 && threadIdx.x == 0) {      // denom for the reduce kernel
        ws->npos = (unsigned int)npos;
        unsigned int nneg = 0;
        // nneg = N - npos only if every label is 0/1 (randint(0,2) => yes)
        nneg = (unsigned int)(N - npos);
        ws->nneg = nneg;
    }

    const int per = (ngroups + GY - 1) / GY;
    const int g0  = by * per;
    const int gn  = min(per, ngroups - g0);  // may be <= 0

    // pass 2: compact + transform ONLY the elements this block consumes
    for (int r = wave; r < NB; r += 4) {
        const float w    = sw[r];
        const float wln2 = w * LN2F;
        int pOff = posBase[r];
        int nIdx = 0;
        const int gB = grpBase[r];
        for (int c0 = 0; c0 < NC; c0 += 64) {
            int c = c0 + lane;
            bool inb = (c < NC);
            float p = inb ? preds[r * NC + c] : 0.0f;
            int   l = inb ? labels[r * NC + c] : -1;
            unsigned long long balP = __ballot(l == 1);
            unsigned long long balN = __ballot(l == 0);
            unsigned long long pre  = (1ull << lane) - 1ull;
            if (l == 1) {
                int rel = pOff + __popcll(balP & pre) - i0;
                if ((unsigned)rel < 1024u)
                    sPos[rel] = make_float2(__expf(-p), w);
            }
            if (l == 0) {
                int idx  = nIdx + __popcll(balN & pre);
                int grel = gB + (idx >> 2) - g0;
                if ((unsigned)grel < (unsigned)gn) {
                    ((float*)&sEG[grel])[idx & 3] = __expf(p);
                    if ((idx & 3) == 0) sWG[grel] = wln2;
                }
            }
            pOff += __popcll(balP);
            nIdx += __popcll(balN);
        }
    }
    __syncthreads();

    // compute: 4 pairs per (group,k): 4 fma + 3 mul + 1 log2 + 1 fma
    const int nI = npos - i0;               // > 0 here
    float F[IPT], PW[IPT], acc[IPT];
    #pragma unroll
    for (int k = 0; k < IPT; ++k) {
        int rel = k * 256 + threadIdx.x;
        if (rel < nI) { float2 s = sPos[rel]; F[k] = s.x; PW[k] = s.y; }
        else          { F[k] = 0.0f; PW[k] = 0.0f; }   // t=1 -> log=0
        acc[k] = 0.0f;
    }

    #pragma unroll 2
    for (int g = 0; g < gn; ++g) {
        float4 e = sEG[g];                  // broadcast ds_read_b128
        float wg = sWG[g];
        #pragma unroll
        for (int k = 0; k < IPT; ++k) {
            float t0 = fmaf(e.x, F[k], 1.0f);
            float t1 = fmaf(e.y, F[k], 1.0f);
            float t2 = fmaf(e.z, F[k], 1.0f);
            float t3 = fmaf(e.w, F[k], 1.0f);
            float m  = (t0 * t1) * (t2 * t3);   // <= ~4e14, no overflow
            acc[k] = fmaf(__log2f(m), wg, acc[k]);
        }
    }

    float a = 0.0f;
    #pragma unroll
    for (int k = 0; k < IPT; ++k) a = fmaf(acc[k], PW[k], a);

    #pragma unroll
    for (int off = 32; off > 0; off >>= 1)
        a += __shfl_down(a, off, 64);

    if (lane == 0) wsum[wave] = a;
    __syncthreads();
    if (threadIdx.x == 0)
        ws->partials[bid] = (double)(wsum[0] + wsum[1] + wsum[2] + wsum[3]);
}

__global__ __launch_bounds__(256) void reduce_kernel(
    const Ws* __restrict__ ws,
    float* __restrict__ out)
{
    double s = 0.0;
    for (int t = threadIdx.x; t < NBLK; t += 256)
        s += ws->partials[t];

    #pragma unroll
    for (int off = 32; off > 0; off >>= 1)
        s += __shfl_down(s, off, 64);

    __shared__ double ds[4];
    const int lane = threadIdx.x & 63;
    const int wid  = threadIdx.x >> 6;
    if (lane == 0) ds[wid] = s;
    __syncthreads();
    if (threadIdx.x == 0) {
        double total = ds[0] + ds[1] + ds[2] + ds[3];
        double denom = (double)ws->npos * (double)ws->nneg;
        out[0] = (float)(total / denom);
    }
}

extern "C" void kernel_launch(void* const* d_in, const int* in_sizes, int n_in,
                              void* d_out, int out_size, void* d_ws, size_t ws_size,
                              hipStream_t stream)
{
    const float* preds  = (const float*)d_in[0];
    const float* sw     = (const float*)d_in[1];
    const int*   labels = (const int*)d_in[2];
    float* out = (float*)d_out;
    Ws* ws = (Ws*)d_ws;

    dim3 grid(GX, GY);
    fused_kernel<<<grid, 256, 0, stream>>>(preds, sw, labels, ws);

    reduce_kernel<<<1, 256, 0, stream>>>(ws, out);
}